// Round 1
// baseline (2029.340 us; speedup 1.0000x reference)
//
#include <hip/hip_runtime.h>
#include <hip/hip_bf16.h>

typedef __hip_bfloat16 bf16;
typedef __attribute__((ext_vector_type(8))) short short8;
typedef __attribute__((ext_vector_type(4))) float f32x4;

#define NN 20000
#define NE 80000
#define DD 128
#define NITER 15
#define HSTRIDE 136   // 272 B row stride: 16B-aligned rows, 2-way LDS aliasing (free)

__device__ inline float bfbits2f(unsigned int hi16) {
  union { unsigned int u; float f; } c; c.u = hi16; return c.f;
}

__device__ inline float readin(const void* p, int i, int fl) {
  return fl ? (float)((const bf16*)p)[i] : ((const float*)p)[i];
}

// ---------------------------------------------------------------------------
// detzero: blocks 0..78 zero counts; block 79 runs dtype detection.
// flag = 1 -> bf16 inputs ; flag = 0 -> fp32 inputs.
// ---------------------------------------------------------------------------
__global__ void detzero_kernel(const unsigned short* __restrict__ x,
                               int* __restrict__ counts, int* __restrict__ flag) {
  const int bid = blockIdx.x, t = threadIdx.x;
  if (bid < 79) {
    int i = bid * 256 + t;
    if (i < NN) counts[i] = 0;
    return;
  }
  __shared__ int cs[256], ct[256];
  int sane = 0, tot = 0;
  for (int i = 2 * t; i < 16384; i += 512) {
    unsigned short v = x[i];
    int e = (v >> 7) & 0xFF;
    tot++;
    if (v == 0 || (e >= 80 && e <= 170)) sane++;
  }
  cs[t] = sane; ct[t] = tot;
  __syncthreads();
  for (int o = 128; o > 0; o >>= 1) {
    if (t < o) { cs[t] += cs[t + o]; ct[t] += ct[t + o]; }
    __syncthreads();
  }
  if (t == 0) *flag = (cs[0] * 10 > ct[0] * 7) ? 1 : 0;
}

// ---------------------------------------------------------------------------
// convert_all: one grid-stride kernel for every input canonicalization.
// ---------------------------------------------------------------------------
#define CX  (NN * DD)
#define CE  (NE * DD)
#define CW0 (NITER * 384 * DD)
#define CW1 (NITER * 128 * DD)
#define CNW0 (NITER * 256 * DD)
#define CB  (NITER * DD)
#define BX0 CX
#define BX1 (BX0 + CE)
#define BX7 (BX1 + CW0 + CW1 + CW1 + CNW0 + CW1 + CW1)
#define BX8 (BX7 + 10 * CB)

struct CvtP {
  const void *x, *e;
  const void* w[6];
  bf16 *xb, *eb;
  bf16* wt[6];
  const void* bs[10];
  float* bd[10];
  const int* flag;
};

__global__ void convert_all(CvtP P) {
  const int fl = *P.flag;
  const int gstride = gridDim.x * 256;
  for (int i = blockIdx.x * 256 + threadIdx.x; i < BX8; i += gstride) {
    if (i < BX0) {
      P.xb[i] = (bf16)readin(P.x, i, fl);
    } else if (i < BX1) {
      P.eb[i - BX0] = (bf16)readin(P.e, i - BX0, fl);
    } else if (i < BX7) {
      int j = i - BX1, w;
      if (j < CW0) { w = 0; }
      else if ((j -= CW0) < CW1) { w = 1; }
      else if ((j -= CW1) < CW1) { w = 2; }
      else if ((j -= CW1) < CNW0) { w = 3; }
      else if ((j -= CNW0) < CW1) { w = 4; }
      else { j -= CW1; w = 5; }
      const int K = (w == 0) ? 384 : (w == 3) ? 256 : 128;
      float v = readin(P.w[w], j, fl);
      int it = j / (K * DD);
      int rem = j - it * K * DD;
      int k = rem >> 7, n = rem & 127;
      P.wt[w][(size_t)it * K * DD + (size_t)n * K + k] = (bf16)v;
    } else {
      int j = i - BX7;
      int b = j / CB, r = j - b * CB;
      P.bd[b][r] = readin(P.bs[b], r, fl);
    }
  }
}

// ---------------------------------------------------------------------------
// Fused 3-layer MLP — BARRIER-FREE version.
//
// Weights per iteration are tiny (<=162 KB) and L2-resident (W1/W2 even fit
// L1). So instead of staging B tiles through a shared LDS double-buffer
// (which forced one __syncthreads + vmcnt(0) DMA drain per 32-K slab — the
// m97-structure stall), every wave reads its B fragments DIRECTLY from
// global into VGPRs. The H tile is wave-private rows in LDS, so with B
// staging gone there is NO cross-wave dependency: zero barriers, waves
// free-run, compiler software-pipelines the slab loop.
//
// MI = row-groups (16 rows each) per wave. Edge MLP uses MI=2 (32 rows/wave,
// 128-row blocks) to amortize each B-fragment read over 2 MFMA; node MLP
// uses MI=1 to keep its grid at 313 blocks (> 256 CUs).
//
// AMODE 1: A0 = concat(xb[row[m]], xb[col[m]], eb[m])  (K0=384)
// AMODE 2: A0 = concat(xb[m], aggb[m])                 (K0=256)
// ---------------------------------------------------------------------------
template<int K0, int AMODE, int MI>
__global__ __launch_bounds__(256, MI == 1 ? 4 : 2) void fused_mlp(
    const bf16* S0b,                 // xb (may alias st for AMODE 2)
    const bf16* S1b,                 // eb (AMODE 1, aliases st) / aggb (AMODE 2)
    const int*  __restrict__ eidx,
    const bf16* __restrict__ W0t, const bf16* __restrict__ W1t,
    const bf16* __restrict__ W2t,
    const float* __restrict__ b0, const float* __restrict__ b1,
    const float* __restrict__ b2,
    const float* __restrict__ gamma, const float* __restrict__ beta,
    bf16* st, int M)
{
  constexpr int RPW = 16 * MI;               // rows per wave
  __shared__ __align__(16) bf16 Hls[64 * MI * HSTRIDE];

  const int tid  = threadIdx.x;
  const int lane = tid & 63;
  const int wv   = tid >> 6;
  const int l15  = lane & 15, quad = lane >> 4;
  const int m0   = blockIdx.x * (64 * MI);

  int rowm[MI], ir[MI], ic[MI];
#pragma unroll
  for (int g = 0; g < MI; g++) {
    rowm[g] = min(m0 + wv * RPW + g * 16 + l15, M - 1);
    if (AMODE == 1) { ir[g] = eidx[rowm[g]]; ic[g] = eidx[NE + rowm[g]]; }
  }

  // 8 per-lane B-fragment base pointers for the current weight matrix.
  const bf16* pB[8];
  auto setB = [&](const bf16* __restrict__ W, int K) {
#pragma unroll
    for (int ni = 0; ni < 8; ni++)
      pB[ni] = W + (size_t)(ni * 16 + l15) * K + quad * 8;
  };

  f32x4 acc[MI][8];
  auto zacc = [&]() {
#pragma unroll
    for (int g = 0; g < MI; g++)
#pragma unroll
      for (int ni = 0; ni < 8; ni++) acc[g][ni] = (f32x4){0.f, 0.f, 0.f, 0.f};
  };

  auto gatherA = [&](int g, int kk) -> short8 {
    const int ks = (kk & 127) + quad * 8;
    const bf16* base;
    if (AMODE == 1) {
      const int seg = kk >> 7;
      base = (seg == 0) ? S0b + (size_t)ir[g] * DD
           : (seg == 1) ? S0b + (size_t)ic[g] * DD
                        : S1b + (size_t)rowm[g] * DD;
    } else {
      base = (kk >> 7) ? S1b + (size_t)rowm[g] * DD
                       : S0b + (size_t)rowm[g] * DD;
    }
    return *(const short8*)(base + ks);
  };

  auto writeH = [&](const float* __restrict__ bias) {
    float bv[8];
#pragma unroll
    for (int ni = 0; ni < 8; ni++) bv[ni] = bias[ni * 16 + l15];
#pragma unroll
    for (int g = 0; g < MI; g++)
#pragma unroll
      for (int r = 0; r < 4; r++) {
        const int row = wv * RPW + g * 16 + quad * 4 + r;
#pragma unroll
        for (int ni = 0; ni < 8; ni++)
          Hls[row * HSTRIDE + ni * 16 + l15] = (bf16)fmaxf(acc[g][ni][r] + bv[ni], 0.f);
      }
  };

  // Phase 1: A gathered from global, B direct from global (L2).
  zacc();
  setB(W0t, K0);
#pragma unroll
  for (int s = 0; s < K0 / 32; s++) {
    const int kk = s * 32;
    short8 bfr[8];
#pragma unroll
    for (int ni = 0; ni < 8; ni++) bfr[ni] = *(const short8*)(pB[ni] + kk);
#pragma unroll
    for (int g = 0; g < MI; g++) {
      short8 a = gatherA(g, kk);
#pragma unroll
      for (int ni = 0; ni < 8; ni++)
        acc[g][ni] = __builtin_amdgcn_mfma_f32_16x16x32_bf16(a, bfr[ni], acc[g][ni], 0, 0, 0);
    }
  }
  writeH(b0);

  // Phase 2: A from wave-private H rows in LDS, B direct from global.
  zacc();
  setB(W1t, 128);
#pragma unroll
  for (int s = 0; s < 4; s++) {
    const int kk = s * 32;
    short8 bfr[8];
#pragma unroll
    for (int ni = 0; ni < 8; ni++) bfr[ni] = *(const short8*)(pB[ni] + kk);
#pragma unroll
    for (int g = 0; g < MI; g++) {
      short8 a = *(const short8*)&Hls[(wv * RPW + g * 16 + l15) * HSTRIDE + kk + quad * 8];
#pragma unroll
      for (int ni = 0; ni < 8; ni++)
        acc[g][ni] = __builtin_amdgcn_mfma_f32_16x16x32_bf16(a, bfr[ni], acc[g][ni], 0, 0, 0);
    }
  }
  writeH(b1);

  // Phase 3 + LN + residual.
  zacc();
  setB(W2t, 128);
#pragma unroll
  for (int s = 0; s < 4; s++) {
    const int kk = s * 32;
    short8 bfr[8];
#pragma unroll
    for (int ni = 0; ni < 8; ni++) bfr[ni] = *(const short8*)(pB[ni] + kk);
#pragma unroll
    for (int g = 0; g < MI; g++) {
      short8 a = *(const short8*)&Hls[(wv * RPW + g * 16 + l15) * HSTRIDE + kk + quad * 8];
#pragma unroll
      for (int ni = 0; ni < 8; ni++)
        acc[g][ni] = __builtin_amdgcn_mfma_f32_16x16x32_bf16(a, bfr[ni], acc[g][ni], 0, 0, 0);
    }
  }

  float bv[8], gv[8], btv[8];
#pragma unroll
  for (int ni = 0; ni < 8; ni++) {
    const int col = ni * 16 + l15;
    bv[ni] = b2[col]; gv[ni] = gamma[col]; btv[ni] = beta[col];
  }
#pragma unroll
  for (int g = 0; g < MI; g++) {
#pragma unroll
    for (int r = 0; r < 4; r++) {
      float a = 0.f, bq = 0.f;
#pragma unroll
      for (int ni = 0; ni < 8; ni++) {
        const float v = acc[g][ni][r] + bv[ni];
        a += v; bq += v * v;
      }
#pragma unroll
      for (int off = 1; off < 16; off <<= 1) {
        a  += __shfl_xor(a, off);
        bq += __shfl_xor(bq, off);
      }
      const float mu = a * (1.0f / 128.0f);
      const float var = fmaxf(bq * (1.0f / 128.0f) - mu * mu, 0.0f);
      const float rs = rsqrtf(var + 1e-5f);
      const int m = m0 + wv * RPW + g * 16 + quad * 4 + r;
      if (m < M) {
#pragma unroll
        for (int ni = 0; ni < 8; ni++) {
          const int col = ni * 16 + l15;
          const float v = acc[g][ni][r] + bv[ni];
          const float lnv = (v - mu) * rs * gv[ni] + btv[ni];
          const size_t idx = (size_t)m * DD + col;
          st[idx] = (bf16)(lnv + (float)st[idx]);
        }
      }
    }
  }
}

// --------------------------- CSR build + aggregate -------------------------
__global__ void hist_kernel(const int* __restrict__ eidx, int* __restrict__ counts) {
  int e = blockIdx.x * 256 + threadIdx.x;
  if (e < NE) atomicAdd(&counts[eidx[NE + e]], 1);
}

__global__ void scan_kernel(const int* __restrict__ counts, int* __restrict__ offs,
                            int* __restrict__ cursor) {
  __shared__ int sums[1024];
  const int t = threadIdx.x;
  const int base = t * 20;
  int local[20];
  int s = 0;
  for (int i = 0; i < 20; i++) {
    int idx = base + i;
    int c = (idx < NN) ? counts[idx] : 0;
    local[i] = s; s += c;
  }
  sums[t] = s;
  __syncthreads();
  for (int off = 1; off < 1024; off <<= 1) {
    int v = 0;
    if (t >= off) v = sums[t - off];
    __syncthreads();
    if (t >= off) sums[t] += v;
    __syncthreads();
  }
  int excl = (t == 0) ? 0 : sums[t - 1];
  for (int i = 0; i < 20; i++) {
    int idx = base + i;
    if (idx < NN) { offs[idx] = excl + local[i]; cursor[idx] = 0; }
  }
  if (t == 1023) offs[NN] = sums[1023];
}

__global__ void fill_kernel(const int* __restrict__ eidx, const int* __restrict__ offs,
                            int* __restrict__ cursor, int* __restrict__ sorted) {
  int e = blockIdx.x * 256 + threadIdx.x;
  if (e < NE) {
    int n = eidx[NE + e];
    int p = atomicAdd(&cursor[n], 1);
    sorted[offs[n] + p] = e;
  }
}

// wave per node (fat grid: 20000 waves, 32 waves/CU -> latency well hidden):
// packed-uint bf16x2 loads, fp32 sums, bf16 out.
__global__ void aggregate_kernel(const bf16* __restrict__ eb, const int* __restrict__ offs,
                                 const int* __restrict__ sorted, bf16* __restrict__ aggb) {
  const int node = blockIdx.x * 4 + (threadIdx.x >> 6);
  const int lane = threadIdx.x & 63;
  if (node >= NN) return;
  const int s = offs[node], t = offs[node + 1];
  float a0 = 0.f, a1 = 0.f;
  for (int i = s; i < t; i++) {
    const int e = sorted[i];
    unsigned int v = *(const unsigned int*)(eb + (size_t)e * DD + 2 * lane);
    a0 += bfbits2f(v << 16);
    a1 += bfbits2f(v & 0xFFFF0000u);
  }
  bf16 o0 = (bf16)a0, o1 = (bf16)a1;
  unsigned int pack = (unsigned int)(*(unsigned short*)&o0)
                    | ((unsigned int)(*(unsigned short*)&o1) << 16);
  *(unsigned int*)(aggb + (size_t)node * DD + 2 * lane) = pack;
}

// bf16 states -> d_out in detected dtype
__global__ void outwb_kernel(const bf16* __restrict__ xb, const bf16* __restrict__ eb,
                             void* __restrict__ out, const int* __restrict__ flag) {
  int i = blockIdx.x * 256 + threadIdx.x;
  const int nx = NN * DD, total = (NN + NE) * DD;
  if (i < total) {
    bf16 v = (i < nx) ? xb[i] : eb[i - nx];
    if (*flag) ((bf16*)out)[i] = v;
    else       ((float*)out)[i] = (float)v;
  }
}

// ---------------------------------------------------------------------------
extern "C" void kernel_launch(void* const* d_in, const int* in_sizes, int n_in,
                              void* d_out, int out_size, void* d_ws, size_t ws_size,
                              hipStream_t stream) {
  const int* eidx = (const int*)d_in[18];

  char* ws = (char*)d_ws;
  size_t off = 0;
  auto alloc = [&](size_t bytes) -> char* {
    char* p = ws + off;
    off = (off + bytes + 255) & ~(size_t)255;
    return p;
  };

  bf16* xb   = (bf16*)alloc((size_t)NN * DD * 2);
  bf16* eb   = (bf16*)alloc((size_t)NE * DD * 2);
  bf16* aggb = (bf16*)alloc((size_t)NN * DD * 2);
  bf16* eW0t = (bf16*)alloc((size_t)CW0 * 2);
  bf16* eW1t = (bf16*)alloc((size_t)CW1 * 2);
  bf16* eW2t = (bf16*)alloc((size_t)CW1 * 2);
  bf16* nW0t = (bf16*)alloc((size_t)CNW0 * 2);
  bf16* nW1t = (bf16*)alloc((size_t)CW1 * 2);
  bf16* nW2t = (bf16*)alloc((size_t)CW1 * 2);
  float* bf_[10];
  for (int i = 0; i < 10; i++) bf_[i] = (float*)alloc(CB * 4);
  int* counts = (int*)alloc((size_t)NN * 4);
  int* cursor = (int*)alloc((size_t)NN * 4);
  int* offs   = (int*)alloc((size_t)(NN + 1) * 4);
  int* sorted = (int*)alloc((size_t)NE * 4);
  int* flag   = (int*)alloc(4);

  // 1) zero counts + detect dtype
  detzero_kernel<<<80, 256, 0, stream>>>((const unsigned short*)d_in[0], counts, flag);

  // 2) all conversions in one kernel
  CvtP C;
  C.x = d_in[0]; C.e = d_in[1];
  C.w[0] = d_in[2];  C.w[1] = d_in[4];  C.w[2] = d_in[6];
  C.w[3] = d_in[10]; C.w[4] = d_in[12]; C.w[5] = d_in[14];
  C.xb = xb; C.eb = eb;
  C.wt[0] = eW0t; C.wt[1] = eW1t; C.wt[2] = eW2t;
  C.wt[3] = nW0t; C.wt[4] = nW1t; C.wt[5] = nW2t;
  const int bsrc_idx[10] = {3, 5, 7, 8, 9, 11, 13, 15, 16, 17};
  for (int i = 0; i < 10; i++) { C.bs[i] = d_in[bsrc_idx[i]]; C.bd[i] = bf_[i]; }
  C.flag = flag;
  convert_all<<<2048, 256, 0, stream>>>(C);

  // 3) CSR
  hist_kernel<<<(NE + 255) / 256, 256, 0, stream>>>(eidx, counts);
  scan_kernel<<<1, 1024, 0, stream>>>(counts, offs, cursor);
  fill_kernel<<<(NE + 255) / 256, 256, 0, stream>>>(eidx, offs, cursor, sorted);

  const int egrid = NE / 128;               // 625 (MI=2: 128-row blocks)
  const int ngrid = (NN + 63) / 64;         // 313 (MI=1: 64-row blocks)

  // 4) message passing: 3 dispatches per iteration
  for (int t = 0; t < NITER; t++) {
    fused_mlp<384, 1, 2><<<egrid, 256, 0, stream>>>(
        xb, eb, eidx,
        eW0t + (size_t)t * 384 * DD, eW1t + (size_t)t * 128 * DD,
        eW2t + (size_t)t * 128 * DD,
        bf_[0] + t * DD, bf_[1] + t * DD, bf_[2] + t * DD,
        bf_[3] + t * DD, bf_[4] + t * DD, eb, NE);
    aggregate_kernel<<<(NN + 3) / 4, 256, 0, stream>>>(eb, offs, sorted, aggb);
    fused_mlp<256, 2, 1><<<ngrid, 256, 0, stream>>>(
        xb, aggb, nullptr,
        nW0t + (size_t)t * 256 * DD, nW1t + (size_t)t * 128 * DD,
        nW2t + (size_t)t * 128 * DD,
        bf_[5] + t * DD, bf_[6] + t * DD, bf_[7] + t * DD,
        bf_[8] + t * DD, bf_[9] + t * DD, xb, NN);
  }

  // 5) output
  outwb_kernel<<<((NN + NE) * DD + 255) / 256, 256, 0, stream>>>(xb, eb, d_out, flag);
}